// Round 5
// baseline (358.422 us; speedup 1.0000x reference)
//
#include <hip/hip_runtime.h>
#include <hip/hip_bf16.h>
#include <stdint.h>

// Sizes (fixed for this problem)
#define NHEADS 16
#define HDIM   64
#define DMODEL 1024
#define SEQ    2048
#define NB     2
#define MTOT   (NB*SEQ)     // 4096 rows of x
#define NTOT   (3*DMODEL)   // 3072 qkv cols
#define KTOT   DMODEL       // 1024

// fold (1/8)*log2(e) into Q so softmax runs in exp2 domain
#define QSCALE 0.18033688011112042f

typedef __attribute__((ext_vector_type(8)))  short          bf16x8;
typedef __attribute__((ext_vector_type(4)))  float          f32x4;
typedef __attribute__((ext_vector_type(8)))  unsigned short u16x8;

__device__ __forceinline__ unsigned short f2bf(float f) {
  unsigned u = __builtin_bit_cast(unsigned, f);
  u += 0x7fffu + ((u >> 16) & 1u);          // round-to-nearest-even
  return (unsigned short)(u >> 16);
}

__device__ __forceinline__ f32x4 vmax4(f32x4 a, f32x4 b) {
  f32x4 r;
  r[0]=fmaxf(a[0],b[0]); r[1]=fmaxf(a[1],b[1]);
  r[2]=fmaxf(a[2],b[2]); r[3]=fmaxf(a[3],b[3]);
  return r;
}

__device__ __forceinline__ void async_copy16(void* lds, const void* g) {
  __builtin_amdgcn_global_load_lds(
      (const __attribute__((address_space(1))) unsigned int*)g,
      (__attribute__((address_space(3))) unsigned int*)lds, 16, 0, 0);
}

// ---------------------------------------------------------------- convert x
__global__ void convert_x_kernel(const float* __restrict__ x,
                                 unsigned short* __restrict__ xb) {
  int i = blockIdx.x * 256 + threadIdx.x;
  const f32x4* xv = reinterpret_cast<const f32x4*>(x);
  f32x4 a = xv[2*i];
  f32x4 b = xv[2*i + 1];
  u16x8 r;
  r[0]=f2bf(a[0]); r[1]=f2bf(a[1]); r[2]=f2bf(a[2]); r[3]=f2bf(a[3]);
  r[4]=f2bf(b[0]); r[5]=f2bf(b[1]); r[6]=f2bf(b[2]); r[7]=f2bf(b[3]);
  reinterpret_cast<u16x8*>(xb)[i] = r;
}

// --------------------------------------- transpose + permute + convert W
__global__ void transpose_w_kernel(const float* __restrict__ W,
                                   unsigned short* __restrict__ Wt) {
  __shared__ float tile[64][65];
  int j0 = blockIdx.x * 64;
  int k0 = blockIdx.y * 64;
  int tid = threadIdx.x;
  int lr = tid >> 6;
  int lc = tid & 63;
  #pragma unroll
  for (int i = 0; i < 16; ++i) {
    int r = i*4 + lr;
    tile[r][lc] = W[(size_t)(k0 + r)*NTOT + j0 + lc];
  }
  __syncthreads();
  #pragma unroll
  for (int i = 0; i < 16; ++i) {
    int jr = i*4 + lr;
    int j  = j0 + jr;
    int oc = (j % 3)*DMODEL + (j / 3);
    Wt[(size_t)oc*KTOT + k0 + lc] = f2bf(tile[lc][jr]);
  }
}

// ---------------------------------------------------------------- QKV GEMM
#define BM 128
#define BN 128
#define BK 64
__launch_bounds__(256)
__global__ void qkv_gemm_kernel(const unsigned short* __restrict__ xb,
                                const unsigned short* __restrict__ wt,
                                const float* __restrict__ bqkv,
                                unsigned short* __restrict__ Qb,
                                unsigned short* __restrict__ Kb,
                                unsigned short* __restrict__ Vt) {
  __shared__ __align__(16) unsigned short As[BM*BK];
  __shared__ __align__(16) unsigned short Bs[BN*BK];
  int tid = threadIdx.x;
  int w = tid >> 6, l = tid & 63;
  int m0 = blockIdx.y * BM;
  int n0 = blockIdx.x * BN;
  int lrow = l >> 3;
  int lcol = (l & 7) * 8;
  int wm = (w >> 1) * 64;
  int wn = (w & 1) * 64;
  int ln = l & 15, lg = l >> 4;

  f32x4 acc[4][4];
  const f32x4 zero4 = {0.f, 0.f, 0.f, 0.f};
  #pragma unroll
  for (int i = 0; i < 4; ++i)
    #pragma unroll
    for (int j = 0; j < 4; ++j) acc[i][j] = zero4;

  for (int kt = 0; kt < KTOT/BK; ++kt) {
    int k0 = kt * BK;
    #pragma unroll
    for (int i = 0; i < 4; ++i) {
      int rbase = w*32 + i*8;
      async_copy16(&As[rbase*BK], &xb[(size_t)(m0 + rbase + lrow)*KTOT + k0 + lcol]);
      async_copy16(&Bs[rbase*BK], &wt[(size_t)(n0 + rbase + lrow)*KTOT + k0 + lcol]);
    }
    asm volatile("s_waitcnt vmcnt(0)" ::: "memory");
    __syncthreads();
    #pragma unroll
    for (int ks = 0; ks < 2; ++ks) {
      bf16x8 af[4], bfr[4];
      #pragma unroll
      for (int mi = 0; mi < 4; ++mi)
        af[mi] = *reinterpret_cast<const bf16x8*>(&As[(wm + mi*16 + ln)*BK + ks*32 + lg*8]);
      #pragma unroll
      for (int ni = 0; ni < 4; ++ni)
        bfr[ni] = *reinterpret_cast<const bf16x8*>(&Bs[(wn + ni*16 + ln)*BK + ks*32 + lg*8]);
      #pragma unroll
      for (int mi = 0; mi < 4; ++mi)
        #pragma unroll
        for (int ni = 0; ni < 4; ++ni)
          acc[mi][ni] = __builtin_amdgcn_mfma_f32_16x16x32_bf16(af[mi], bfr[ni], acc[mi][ni], 0, 0, 0);
    }
    __syncthreads();
  }

  int r4 = lg * 4;
  #pragma unroll
  for (int mi = 0; mi < 4; ++mi) {
    #pragma unroll
    for (int ni = 0; ni < 4; ++ni) {
      int nc = n0 + wn + ni*16 + ln;
      int c  = nc >> 10;
      int hd = nc & 1023;
      int h = hd >> 6, d = hd & 63;
      float bias = bqkv[hd*3 + c];
      float qs = (c == 0) ? QSCALE : 1.0f;   // fold softmax scale into Q
      #pragma unroll
      for (int j = 0; j < 4; ++j) {
        int m = m0 + wm + mi*16 + r4 + j;
        int n = m >> 11, t = m & 2047;
        unsigned short val = f2bf((acc[mi][ni][j] + bias) * qs);
        size_t nh = (size_t)(n*NHEADS + h);
        if (c == 0)      Qb[((nh*SEQ + t) << 6) + d] = val;
        else if (c == 1) Kb[((nh*SEQ + t) << 6) + d] = val;
        else             Vt[((nh*HDIM + d) << 11) + t] = val;
      }
    }
  }
}

// ---------------------------------------------------------------- attention
// Split-K flash attention, 16x16x32 MFMA pieces (layouts HW-validated in R1/R4):
//   A-frag: row=l&15, k=8*(l>>4)+j   B-frag: col=l&15, k=8*(l>>4)+j
//   C/D   : col=l&15, row=4*(l>>4)+reg
// Block = 4 waves = 2 q-subtiles x 2 key-halves (1024 keys each, 16 tiles of 64).
// Steady-state tile has ZERO cross-lane ops: per-lane local max + __all defer-max
// (T13), per-lane psum4 accumulation (row-sum reduced once after the loop).
// Wave-pairs merge (m, l, o) partials via LDS + one __syncthreads.
#define PROW   72                 // padded P row, bf16 elems (144 B)
#define REGION 4352               // bytes per wave region: 16 rows x 68 f32
__launch_bounds__(256, 6)
__global__ void attn_kernel(const unsigned short* __restrict__ Qb,
                            const unsigned short* __restrict__ Kb,
                            const unsigned short* __restrict__ Vt,
                            float* __restrict__ out) {
  __shared__ __align__(16) unsigned char smem[4*REGION + 512]; // 17920 B
  int tid = threadIdx.x;
  int w = tid >> 6, l = tid & 63;
  int ln = l & 15, lg = l >> 4;

  unsigned short* Pw  = (unsigned short*)(smem + w * REGION); // P (loop)
  float*          obw = (float*)         (smem + w * REGION); // o (aliased, post-loop)
  float*          mlp = (float*)         (smem + 4 * REGION); // [4][2][16]

  // XCD clustering: 2048 blocks, 8 XCDs -> each XCD owns 4 heads
  int fid  = blockIdx.x;
  int xcd  = fid & 7, idx = fid >> 3;       // idx 0..255
  int bh   = xcd * 4 + (idx >> 6);          // 0..31
  int qblk = idx & 63;                      // 0..63 (32 q-rows each)
  int half = w & 1;                         // key half
  int qs_i = w >> 1;                        // q-subtile within block
  int q0   = qblk * 32 + qs_i * 16;

  const unsigned short* Qh = Qb + (size_t)bh * SEQ * HDIM;
  const unsigned short* Kh = Kb + (size_t)bh * SEQ * HDIM + (size_t)half * 1024 * HDIM;
  const unsigned short* Vh = Vt + (size_t)bh * HDIM * SEQ + (size_t)half * 1024;

  // Q B-fragments (col = q = ln), d-windows dw=0,1
  bf16x8 qf[2];
  #pragma unroll
  for (int dw = 0; dw < 2; ++dw)
    qf[dw] = *reinterpret_cast<const bf16x8*>(&Qh[(size_t)(q0 + ln)*HDIM + dw*32 + lg*8]);

  const f32x4 zero4 = {0.f, 0.f, 0.f, 0.f};
  f32x4 o[4];
  #pragma unroll
  for (int db = 0; db < 4; ++db) o[db] = zero4;
  f32x4 psum4 = zero4;
  float mrow = -INFINITY;

  for (int kv = 0; kv < 16; ++kv) {
    int key0 = kv * 64;

    // ---- S^T: 4 key-blocks x 2 d-windows
    f32x4 s[4];
    #pragma unroll
    for (int kb = 0; kb < 4; ++kb) {
      bf16x8 k0 = *reinterpret_cast<const bf16x8*>(
          &Kh[(size_t)(key0 + kb*16 + ln)*HDIM + lg*8]);
      bf16x8 k1 = *reinterpret_cast<const bf16x8*>(
          &Kh[(size_t)(key0 + kb*16 + ln)*HDIM + 32 + lg*8]);
      f32x4 t0 = __builtin_amdgcn_mfma_f32_16x16x32_bf16(k0, qf[0], zero4, 0, 0, 0);
      s[kb]    = __builtin_amdgcn_mfma_f32_16x16x32_bf16(k1, qf[1], t0,    0, 0, 0);
    }

    // ---- per-lane local max over this lane's 16 keys (no cross-lane!)
    f32x4 m4 = vmax4(vmax4(s[0], s[1]), vmax4(s[2], s[3]));
    float localmax = fmaxf(fmaxf(m4[0], m4[1]), fmaxf(m4[2], m4[3]));

    // ---- T13 defer-max: full reduce+rescale only when max grows (rare)
    if (!__all(localmax <= mrow + 8.f)) {
      float pm = localmax;
      pm = fmaxf(pm, __shfl_xor(pm, 16));
      pm = fmaxf(pm, __shfl_xor(pm, 32));
      float mn  = fmaxf(mrow, pm);
      float scl = __builtin_amdgcn_exp2f(mrow - mn);
      mrow = mn;
      psum4 *= scl;
      #pragma unroll
      for (int db = 0; db < 4; ++db)
        #pragma unroll
        for (int r = 0; r < 4; ++r) o[db][r] *= scl;
    }

    // ---- P = exp2(S - m); accumulate per-lane partial sums in registers
    #pragma unroll
    for (int kb = 0; kb < 4; ++kb) {
      #pragma unroll
      for (int r = 0; r < 4; ++r)
        s[kb][r] = __builtin_amdgcn_exp2f(s[kb][r] - mrow);
      psum4 += s[kb];
    }

    // ---- P -> LDS, row q=ln, col key (validated f2bf pair packing)
    #pragma unroll
    for (int kb = 0; kb < 4; ++kb) {
      unsigned pa = (unsigned)f2bf(s[kb][0]) | ((unsigned)f2bf(s[kb][1]) << 16);
      unsigned pb = (unsigned)f2bf(s[kb][2]) | ((unsigned)f2bf(s[kb][3]) << 16);
      uint2 pk; pk.x = pa; pk.y = pb;
      *reinterpret_cast<uint2*>(&Pw[ln*PROW + kb*16 + 4*lg]) = pk;
    }

    // ---- PV: A = V^T chunk (from global), B = P^T from LDS
    #pragma unroll
    for (int kw = 0; kw < 2; ++kw) {
      bf16x8 pb = *reinterpret_cast<const bf16x8*>(&Pw[ln*PROW + kw*32 + lg*8]);
      #pragma unroll
      for (int db = 0; db < 4; ++db) {
        bf16x8 vfr = *reinterpret_cast<const bf16x8*>(
            &Vh[(size_t)(db*16 + ln)*SEQ + key0 + kw*32 + lg*8]);
        o[db] = __builtin_amdgcn_mfma_f32_16x16x32_bf16(vfr, pb, o[db], 0, 0, 0);
      }
    }
  }

  // ---- post-loop: row-sum reduce (once), publish partials to LDS
  float ls = (psum4[0] + psum4[1]) + (psum4[2] + psum4[3]);
  ls += __shfl_xor(ls, 16);
  ls += __shfl_xor(ls, 32);

  #pragma unroll
  for (int db = 0; db < 4; ++db)
    #pragma unroll
    for (int r = 0; r < 4; ++r)
      obw[ln*68 + db*16 + 4*lg + r] = o[db][r];
  if (l < 16) {
    mlp[w*32 + l]      = mrow;   // per-row running max (row = l)
    mlp[w*32 + 16 + l] = ls;     // per-row sum
  }
  __syncthreads();

  // ---- merge key-halves: wave pair (2*qs_i, 2*qs_i+1); this wave does 8 rows
  int pa_ = qs_i * 2;
  const float* oa = (const float*)(smem + pa_ * REGION);
  const float* ob = (const float*)(smem + (pa_ + 1) * REGION);
  int n = bh >> 4, h = bh & 15;
  #pragma unroll
  for (int p = 0; p < 2; ++p) {
    int qr = half*8 + p*4 + lg;            // row 0..15 within q-subtile
    float ma = mlp[pa_*32 + qr],       la = mlp[pa_*32 + 16 + qr];
    float mb = mlp[(pa_+1)*32 + qr],   lb = mlp[(pa_+1)*32 + 16 + qr];
    float mM = fmaxf(ma, mb);
    float sa = __builtin_amdgcn_exp2f(ma - mM);
    float sb = __builtin_amdgcn_exp2f(mb - mM);
    float inv = 1.f / (la*sa + lb*sb);
    f32x4 va = *reinterpret_cast<const f32x4*>(&oa[qr*68 + 4*ln]);
    f32x4 vb = *reinterpret_cast<const f32x4*>(&ob[qr*68 + 4*ln]);
    f32x4 res;
    #pragma unroll
    for (int r = 0; r < 4; ++r) res[r] = (va[r]*sa + vb[r]*sb) * inv;
    int qg = qblk*32 + qs_i*16 + qr;
    *reinterpret_cast<f32x4*>(
        &out[((size_t)(n*SEQ + qg))*DMODEL + h*HDIM + 4*ln]) = res;
  }
}

// ---------------------------------------------------------------- launcher
extern "C" void kernel_launch(void* const* d_in, const int* in_sizes, int n_in,
                              void* d_out, int out_size, void* d_ws, size_t ws_size,
                              hipStream_t stream) {
  const float* x    = (const float*)d_in[0];
  // d_in[1] = mask: constant shift along query axis inside softmax -> no-op
  const float* Wq   = (const float*)d_in[2];
  const float* bq   = (const float*)d_in[3];
  float* out = (float*)d_out;

  unsigned short* xb = (unsigned short*)d_ws;                    // [4096][1024]
  unsigned short* wt = xb + (size_t)MTOT*KTOT;                   // [3072][1024]
  unsigned short* Qb = wt + (size_t)NTOT*KTOT;                   // [32][2048][64]
  unsigned short* Kb = Qb + (size_t)NB*NHEADS*SEQ*HDIM;          // [32][2048][64]
  unsigned short* Vt = Kb + (size_t)NB*NHEADS*SEQ*HDIM;          // [32][64][2048]

  convert_x_kernel<<<(MTOT*KTOT/8)/256, 256, 0, stream>>>(x, xb);
  transpose_w_kernel<<<dim3(NTOT/64, KTOT/64), 256, 0, stream>>>(Wq, wt);
  qkv_gemm_kernel<<<dim3(NTOT/BN, MTOT/BM), 256, 0, stream>>>(xb, wt, bq, Qb, Kb, Vt);
  attn_kernel<<<2048, 256, 0, stream>>>(Qb, Kb, Vt, out);
}

// Round 6
// 304.908 us; speedup vs baseline: 1.1755x; 1.1755x over previous
//
#include <hip/hip_runtime.h>
#include <hip/hip_bf16.h>
#include <stdint.h>

// Sizes (fixed for this problem)
#define NHEADS 16
#define HDIM   64
#define DMODEL 1024
#define SEQ    2048
#define NB     2
#define MTOT   (NB*SEQ)     // 4096 rows of x
#define NTOT   (3*DMODEL)   // 3072 qkv cols
#define KTOT   DMODEL       // 1024

// fold (1/8)*log2(e) into Q so softmax runs in exp2 domain
#define QSCALE 0.18033688011112042f

typedef __attribute__((ext_vector_type(8)))  short          bf16x8;
typedef __attribute__((ext_vector_type(4)))  float          f32x4;
typedef __attribute__((ext_vector_type(8)))  unsigned short u16x8;

__device__ __forceinline__ unsigned short f2bf(float f) {
  unsigned u = __builtin_bit_cast(unsigned, f);
  u += 0x7fffu + ((u >> 16) & 1u);          // round-to-nearest-even
  return (unsigned short)(u >> 16);
}

__device__ __forceinline__ f32x4 vmax4(f32x4 a, f32x4 b) {
  f32x4 r;
  r[0]=fmaxf(a[0],b[0]); r[1]=fmaxf(a[1],b[1]);
  r[2]=fmaxf(a[2],b[2]); r[3]=fmaxf(a[3],b[3]);
  return r;
}

__device__ __forceinline__ void async_copy16(void* lds, const void* g) {
  __builtin_amdgcn_global_load_lds(
      (const __attribute__((address_space(1))) unsigned int*)g,
      (__attribute__((address_space(3))) unsigned int*)lds, 16, 0, 0);
}

// ---------------------------------------------------------------- convert x
__global__ void convert_x_kernel(const float* __restrict__ x,
                                 unsigned short* __restrict__ xb) {
  int i = blockIdx.x * 256 + threadIdx.x;
  const f32x4* xv = reinterpret_cast<const f32x4*>(x);
  f32x4 a = xv[2*i];
  f32x4 b = xv[2*i + 1];
  u16x8 r;
  r[0]=f2bf(a[0]); r[1]=f2bf(a[1]); r[2]=f2bf(a[2]); r[3]=f2bf(a[3]);
  r[4]=f2bf(b[0]); r[5]=f2bf(b[1]); r[6]=f2bf(b[2]); r[7]=f2bf(b[3]);
  reinterpret_cast<u16x8*>(xb)[i] = r;
}

// --------------------------------------- transpose + permute + convert W
__global__ void transpose_w_kernel(const float* __restrict__ W,
                                   unsigned short* __restrict__ Wt) {
  __shared__ float tile[64][65];
  int j0 = blockIdx.x * 64;
  int k0 = blockIdx.y * 64;
  int tid = threadIdx.x;
  int lr = tid >> 6;
  int lc = tid & 63;
  #pragma unroll
  for (int i = 0; i < 16; ++i) {
    int r = i*4 + lr;
    tile[r][lc] = W[(size_t)(k0 + r)*NTOT + j0 + lc];
  }
  __syncthreads();
  #pragma unroll
  for (int i = 0; i < 16; ++i) {
    int jr = i*4 + lr;
    int j  = j0 + jr;
    int oc = (j % 3)*DMODEL + (j / 3);
    Wt[(size_t)oc*KTOT + k0 + lc] = f2bf(tile[lc][jr]);
  }
}

// ---------------------------------------------------------------- QKV GEMM
#define BM 128
#define BN 128
#define BK 64
__launch_bounds__(256)
__global__ void qkv_gemm_kernel(const unsigned short* __restrict__ xb,
                                const unsigned short* __restrict__ wt,
                                const float* __restrict__ bqkv,
                                unsigned short* __restrict__ Qb,
                                unsigned short* __restrict__ Kb,
                                unsigned short* __restrict__ Vt) {
  __shared__ __align__(16) unsigned short As[BM*BK];
  __shared__ __align__(16) unsigned short Bs[BN*BK];
  int tid = threadIdx.x;
  int w = tid >> 6, l = tid & 63;
  int m0 = blockIdx.y * BM;
  int n0 = blockIdx.x * BN;
  int lrow = l >> 3;
  int lcol = (l & 7) * 8;
  int wm = (w >> 1) * 64;
  int wn = (w & 1) * 64;
  int ln = l & 15, lg = l >> 4;

  f32x4 acc[4][4];
  const f32x4 zero4 = {0.f, 0.f, 0.f, 0.f};
  #pragma unroll
  for (int i = 0; i < 4; ++i)
    #pragma unroll
    for (int j = 0; j < 4; ++j) acc[i][j] = zero4;

  for (int kt = 0; kt < KTOT/BK; ++kt) {
    int k0 = kt * BK;
    #pragma unroll
    for (int i = 0; i < 4; ++i) {
      int rbase = w*32 + i*8;
      async_copy16(&As[rbase*BK], &xb[(size_t)(m0 + rbase + lrow)*KTOT + k0 + lcol]);
      async_copy16(&Bs[rbase*BK], &wt[(size_t)(n0 + rbase + lrow)*KTOT + k0 + lcol]);
    }
    asm volatile("s_waitcnt vmcnt(0)" ::: "memory");
    __syncthreads();
    #pragma unroll
    for (int ks = 0; ks < 2; ++ks) {
      bf16x8 af[4], bfr[4];
      #pragma unroll
      for (int mi = 0; mi < 4; ++mi)
        af[mi] = *reinterpret_cast<const bf16x8*>(&As[(wm + mi*16 + ln)*BK + ks*32 + lg*8]);
      #pragma unroll
      for (int ni = 0; ni < 4; ++ni)
        bfr[ni] = *reinterpret_cast<const bf16x8*>(&Bs[(wn + ni*16 + ln)*BK + ks*32 + lg*8]);
      #pragma unroll
      for (int mi = 0; mi < 4; ++mi)
        #pragma unroll
        for (int ni = 0; ni < 4; ++ni)
          acc[mi][ni] = __builtin_amdgcn_mfma_f32_16x16x32_bf16(af[mi], bfr[ni], acc[mi][ni], 0, 0, 0);
    }
    __syncthreads();
  }

  int r4 = lg * 4;
  #pragma unroll
  for (int mi = 0; mi < 4; ++mi) {
    #pragma unroll
    for (int ni = 0; ni < 4; ++ni) {
      int nc = n0 + wn + ni*16 + ln;
      int c  = nc >> 10;
      int hd = nc & 1023;
      int h = hd >> 6, d = hd & 63;
      float bias = bqkv[hd*3 + c];
      float qs = (c == 0) ? QSCALE : 1.0f;   // fold softmax scale into Q
      #pragma unroll
      for (int j = 0; j < 4; ++j) {
        int m = m0 + wm + mi*16 + r4 + j;
        int n = m >> 11, t = m & 2047;
        unsigned short val = f2bf((acc[mi][ni][j] + bias) * qs);
        size_t nh = (size_t)(n*NHEADS + h);
        if (c == 0)      Qb[((nh*SEQ + t) << 6) + d] = val;
        else if (c == 1) Kb[((nh*SEQ + t) << 6) + d] = val;
        else             Vt[((nh*HDIM + d) << 11) + t] = val;
      }
    }
  }
}

// ---------------------------------------------------------------- attention
// Split-K flash attention, 16x16x32 MFMA pieces (layouts HW-validated R1/R4/R5):
//   A-frag: row=l&15, k=8*(l>>4)+j   B-frag: col=l&15, k=8*(l>>4)+j
//   C/D   : col=l&15, row=4*(l>>4)+reg
// Block = 4 waves = 2 q-subtiles x 2 key-halves (1024 keys each, 16 tiles).
// R6 change vs R5: explicit per-wave software pipeline —
//   V(i) loads issued at iteration top (cover = QK + softmax + LDS),
//   K(i+1) loads re-issued into the same regs right after QK consumes K(i)
//   (cover = softmax + LDS + PV). launch_bounds(256,4): VGPR cap 128 so the
//   compiler can actually keep 16 loads in flight (R5's cap of 6 waves ->
//   VGPR=36 serialized all loads; that was the regression).
#define PROW   72                 // padded P row, bf16 elems (144 B)
#define REGION 4352               // bytes per wave region: 16 rows x 68 f32
__launch_bounds__(256, 4)
__global__ void attn_kernel(const unsigned short* __restrict__ Qb,
                            const unsigned short* __restrict__ Kb,
                            const unsigned short* __restrict__ Vt,
                            float* __restrict__ out) {
  __shared__ __align__(16) unsigned char smem[4*REGION + 512]; // 17920 B
  int tid = threadIdx.x;
  int w = tid >> 6, l = tid & 63;
  int ln = l & 15, lg = l >> 4;

  unsigned short* Pw  = (unsigned short*)(smem + w * REGION); // P (loop)
  float*          obw = (float*)         (smem + w * REGION); // o (aliased, post-loop)
  float*          mlp = (float*)         (smem + 4 * REGION); // [4][2][16]

  // XCD clustering: 2048 blocks, 8 XCDs -> each XCD owns 4 heads
  int fid  = blockIdx.x;
  int xcd  = fid & 7, idx = fid >> 3;       // idx 0..255
  int bh   = xcd * 4 + (idx >> 6);          // 0..31
  int qblk = idx & 63;                      // 0..63 (32 q-rows each)
  int half = w & 1;                         // key half
  int qs_i = w >> 1;                        // q-subtile within block
  int q0   = qblk * 32 + qs_i * 16;

  const unsigned short* Qh = Qb + (size_t)bh * SEQ * HDIM;
  const unsigned short* Kh = Kb + (size_t)bh * SEQ * HDIM + (size_t)half * 1024 * HDIM;
  const unsigned short* Vh = Vt + (size_t)bh * HDIM * SEQ + (size_t)half * 1024;

  // Q B-fragments (col = q = ln), d-windows dw=0,1
  bf16x8 qf[2];
  #pragma unroll
  for (int dw = 0; dw < 2; ++dw)
    qf[dw] = *reinterpret_cast<const bf16x8*>(&Qh[(size_t)(q0 + ln)*HDIM + dw*32 + lg*8]);

  const f32x4 zero4 = {0.f, 0.f, 0.f, 0.f};
  f32x4 o[4];
  #pragma unroll
  for (int db = 0; db < 4; ++db) o[db] = zero4;
  f32x4 psum4 = zero4;
  float mrow = -INFINITY;

  bf16x8 kf[8];      // current K tile (prefetched)
  bf16x8 vf[2][4];   // current V tile (issued at iteration top)

  #define LOADK(KEY0)                                                         \
  do {                                                                        \
    _Pragma("unroll")                                                         \
    for (int kb = 0; kb < 4; ++kb) {                                          \
      kf[kb*2]   = *reinterpret_cast<const bf16x8*>(                          \
          &Kh[(size_t)((KEY0) + kb*16 + ln)*HDIM + lg*8]);                    \
      kf[kb*2+1] = *reinterpret_cast<const bf16x8*>(                          \
          &Kh[(size_t)((KEY0) + kb*16 + ln)*HDIM + 32 + lg*8]);               \
    }                                                                         \
  } while (0)

  LOADK(0);

  for (int kv = 0; kv < 16; ++kv) {
    int key0 = kv * 64;

    // ---- issue V loads for THIS tile first (land during softmax+LDS)
    #pragma unroll
    for (int kw = 0; kw < 2; ++kw)
      #pragma unroll
      for (int db = 0; db < 4; ++db)
        vf[kw][db] = *reinterpret_cast<const bf16x8*>(
            &Vh[(size_t)(db*16 + ln)*SEQ + key0 + kw*32 + lg*8]);

    // ---- S^T: consume current K regs
    f32x4 s[4];
    #pragma unroll
    for (int kb = 0; kb < 4; ++kb) {
      f32x4 t0 = __builtin_amdgcn_mfma_f32_16x16x32_bf16(kf[kb*2],   qf[0], zero4, 0, 0, 0);
      s[kb]    = __builtin_amdgcn_mfma_f32_16x16x32_bf16(kf[kb*2+1], qf[1], t0,    0, 0, 0);
    }

    // ---- prefetch K for next tile into the SAME regs (WAR after MFMA)
    int nkey = (kv < 15) ? key0 + 64 : key0;
    LOADK(nkey);

    // ---- per-lane local max over this lane's 16 keys (no cross-lane!)
    f32x4 m4 = vmax4(vmax4(s[0], s[1]), vmax4(s[2], s[3]));
    float localmax = fmaxf(fmaxf(m4[0], m4[1]), fmaxf(m4[2], m4[3]));

    // ---- T13 defer-max: full reduce+rescale only when max grows (rare)
    if (!__all(localmax <= mrow + 8.f)) {
      float pm = localmax;
      pm = fmaxf(pm, __shfl_xor(pm, 16));
      pm = fmaxf(pm, __shfl_xor(pm, 32));
      float mn  = fmaxf(mrow, pm);
      float scl = __builtin_amdgcn_exp2f(mrow - mn);
      mrow = mn;
      psum4 *= scl;
      #pragma unroll
      for (int db = 0; db < 4; ++db)
        #pragma unroll
        for (int r = 0; r < 4; ++r) o[db][r] *= scl;
    }

    // ---- P = exp2(S - m); accumulate per-lane partial sums in registers
    #pragma unroll
    for (int kb = 0; kb < 4; ++kb) {
      #pragma unroll
      for (int r = 0; r < 4; ++r)
        s[kb][r] = __builtin_amdgcn_exp2f(s[kb][r] - mrow);
      psum4 += s[kb];
    }

    // ---- P -> LDS, row q=ln, col key (validated f2bf pair packing)
    #pragma unroll
    for (int kb = 0; kb < 4; ++kb) {
      unsigned pa = (unsigned)f2bf(s[kb][0]) | ((unsigned)f2bf(s[kb][1]) << 16);
      unsigned pb = (unsigned)f2bf(s[kb][2]) | ((unsigned)f2bf(s[kb][3]) << 16);
      uint2 pk; pk.x = pa; pk.y = pb;
      *reinterpret_cast<uint2*>(&Pw[ln*PROW + kb*16 + 4*lg]) = pk;
    }

    // ---- PV: A = V^T chunk (regs, loaded at top), B = P^T from LDS
    #pragma unroll
    for (int kw = 0; kw < 2; ++kw) {
      bf16x8 pb = *reinterpret_cast<const bf16x8*>(&Pw[ln*PROW + kw*32 + lg*8]);
      #pragma unroll
      for (int db = 0; db < 4; ++db)
        o[db] = __builtin_amdgcn_mfma_f32_16x16x32_bf16(vf[kw][db], pb, o[db], 0, 0, 0);
    }
  }
  #undef LOADK

  // ---- post-loop: row-sum reduce (once), publish partials to LDS
  float ls = (psum4[0] + psum4[1]) + (psum4[2] + psum4[3]);
  ls += __shfl_xor(ls, 16);
  ls += __shfl_xor(ls, 32);

  #pragma unroll
  for (int db = 0; db < 4; ++db)
    #pragma unroll
    for (int r = 0; r < 4; ++r)
      obw[ln*68 + db*16 + 4*lg + r] = o[db][r];
  if (l < 16) {
    mlp[w*32 + l]      = mrow;   // per-row running max (row = l)
    mlp[w*32 + 16 + l] = ls;     // per-row sum
  }
  __syncthreads();

  // ---- merge key-halves: wave pair (2*qs_i, 2*qs_i+1); this wave does 8 rows
  int pa_ = qs_i * 2;
  const float* oa = (const float*)(smem + pa_ * REGION);
  const float* ob = (const float*)(smem + (pa_ + 1) * REGION);
  int n = bh >> 4, h = bh & 15;
  #pragma unroll
  for (int p = 0; p < 2; ++p) {
    int qr = half*8 + p*4 + lg;            // row 0..15 within q-subtile
    float ma = mlp[pa_*32 + qr],       la = mlp[pa_*32 + 16 + qr];
    float mb = mlp[(pa_+1)*32 + qr],   lb = mlp[(pa_+1)*32 + 16 + qr];
    float mM = fmaxf(ma, mb);
    float sa = __builtin_amdgcn_exp2f(ma - mM);
    float sb = __builtin_amdgcn_exp2f(mb - mM);
    float inv = 1.f / (la*sa + lb*sb);
    f32x4 va = *reinterpret_cast<const f32x4*>(&oa[qr*68 + 4*ln]);
    f32x4 vb = *reinterpret_cast<const f32x4*>(&ob[qr*68 + 4*ln]);
    f32x4 res;
    #pragma unroll
    for (int r = 0; r < 4; ++r) res[r] = (va[r]*sa + vb[r]*sb) * inv;
    int qg = qblk*32 + qs_i*16 + qr;
    *reinterpret_cast<f32x4*>(
        &out[((size_t)(n*SEQ + qg))*DMODEL + h*HDIM + 4*ln]) = res;
  }
}

// ---------------------------------------------------------------- launcher
extern "C" void kernel_launch(void* const* d_in, const int* in_sizes, int n_in,
                              void* d_out, int out_size, void* d_ws, size_t ws_size,
                              hipStream_t stream) {
  const float* x    = (const float*)d_in[0];
  // d_in[1] = mask: constant shift along query axis inside softmax -> no-op
  const float* Wq   = (const float*)d_in[2];
  const float* bq   = (const float*)d_in[3];
  float* out = (float*)d_out;

  unsigned short* xb = (unsigned short*)d_ws;                    // [4096][1024]
  unsigned short* wt = xb + (size_t)MTOT*KTOT;                   // [3072][1024]
  unsigned short* Qb = wt + (size_t)NTOT*KTOT;                   // [32][2048][64]
  unsigned short* Kb = Qb + (size_t)NB*NHEADS*SEQ*HDIM;          // [32][2048][64]
  unsigned short* Vt = Kb + (size_t)NB*NHEADS*SEQ*HDIM;          // [32][64][2048]

  convert_x_kernel<<<(MTOT*KTOT/8)/256, 256, 0, stream>>>(x, xb);
  transpose_w_kernel<<<dim3(NTOT/64, KTOT/64), 256, 0, stream>>>(Wq, wt);
  qkv_gemm_kernel<<<dim3(NTOT/BN, MTOT/BM), 256, 0, stream>>>(xb, wt, bq, Qb, Kb, Vt);
  attn_kernel<<<2048, 256, 0, stream>>>(Qb, Kb, Vt, out);
}

// Round 7
// 148.911 us; speedup vs baseline: 2.4070x; 2.0476x over previous
//
#include <hip/hip_runtime.h>
#include <hip/hip_bf16.h>
#include <stdint.h>

// Sizes (fixed for this problem)
#define NHEADS 16
#define HDIM   64
#define DMODEL 1024
#define SEQ    2048
#define NB     2
#define MTOT   (NB*SEQ)     // 4096 rows of x
#define NTOT   (3*DMODEL)   // 3072 qkv cols
#define KTOT   DMODEL       // 1024

// fold (1/8)*log2(e) into Q so softmax runs in exp2 domain
#define QSCALE 0.18033688011112042f

typedef __attribute__((ext_vector_type(8)))  short          bf16x8;
typedef __attribute__((ext_vector_type(4)))  float          f32x4;
typedef __attribute__((ext_vector_type(8)))  unsigned short u16x8;

__device__ __forceinline__ unsigned short f2bf(float f) {
  unsigned u = __builtin_bit_cast(unsigned, f);
  u += 0x7fffu + ((u >> 16) & 1u);          // round-to-nearest-even
  return (unsigned short)(u >> 16);
}

__device__ __forceinline__ f32x4 vmax4(f32x4 a, f32x4 b) {
  f32x4 r;
  r[0]=fmaxf(a[0],b[0]); r[1]=fmaxf(a[1],b[1]);
  r[2]=fmaxf(a[2],b[2]); r[3]=fmaxf(a[3],b[3]);
  return r;
}

__device__ __forceinline__ void async_copy16(void* lds, const void* g) {
  __builtin_amdgcn_global_load_lds(
      (const __attribute__((address_space(1))) unsigned int*)g,
      (__attribute__((address_space(3))) unsigned int*)lds, 16, 0, 0);
}

// ---------------------------------------------------------------- convert x
__global__ void convert_x_kernel(const float* __restrict__ x,
                                 unsigned short* __restrict__ xb) {
  int i = blockIdx.x * 256 + threadIdx.x;
  const f32x4* xv = reinterpret_cast<const f32x4*>(x);
  f32x4 a = xv[2*i];
  f32x4 b = xv[2*i + 1];
  u16x8 r;
  r[0]=f2bf(a[0]); r[1]=f2bf(a[1]); r[2]=f2bf(a[2]); r[3]=f2bf(a[3]);
  r[4]=f2bf(b[0]); r[5]=f2bf(b[1]); r[6]=f2bf(b[2]); r[7]=f2bf(b[3]);
  reinterpret_cast<u16x8*>(xb)[i] = r;
}

// --------------------------------------- transpose + permute + convert W
__global__ void transpose_w_kernel(const float* __restrict__ W,
                                   unsigned short* __restrict__ Wt) {
  __shared__ float tile[64][65];
  int j0 = blockIdx.x * 64;
  int k0 = blockIdx.y * 64;
  int tid = threadIdx.x;
  int lr = tid >> 6;
  int lc = tid & 63;
  #pragma unroll
  for (int i = 0; i < 16; ++i) {
    int r = i*4 + lr;
    tile[r][lc] = W[(size_t)(k0 + r)*NTOT + j0 + lc];
  }
  __syncthreads();
  #pragma unroll
  for (int i = 0; i < 16; ++i) {
    int jr = i*4 + lr;
    int j  = j0 + jr;
    int oc = (j % 3)*DMODEL + (j / 3);
    Wt[(size_t)oc*KTOT + k0 + lc] = f2bf(tile[lc][jr]);
  }
}

// ---------------------------------------------------------------- QKV GEMM
#define BM 128
#define BN 128
#define BK 64
__launch_bounds__(256)
__global__ void qkv_gemm_kernel(const unsigned short* __restrict__ xb,
                                const unsigned short* __restrict__ wt,
                                const float* __restrict__ bqkv,
                                unsigned short* __restrict__ Qb,
                                unsigned short* __restrict__ Kb,
                                unsigned short* __restrict__ Vt) {
  __shared__ __align__(16) unsigned short As[BM*BK];
  __shared__ __align__(16) unsigned short Bs[BN*BK];
  int tid = threadIdx.x;
  int w = tid >> 6, l = tid & 63;
  int m0 = blockIdx.y * BM;
  int n0 = blockIdx.x * BN;
  int lrow = l >> 3;
  int lcol = (l & 7) * 8;
  int wm = (w >> 1) * 64;
  int wn = (w & 1) * 64;
  int ln = l & 15, lg = l >> 4;

  f32x4 acc[4][4];
  const f32x4 zero4 = {0.f, 0.f, 0.f, 0.f};
  #pragma unroll
  for (int i = 0; i < 4; ++i)
    #pragma unroll
    for (int j = 0; j < 4; ++j) acc[i][j] = zero4;

  for (int kt = 0; kt < KTOT/BK; ++kt) {
    int k0 = kt * BK;
    #pragma unroll
    for (int i = 0; i < 4; ++i) {
      int rbase = w*32 + i*8;
      async_copy16(&As[rbase*BK], &xb[(size_t)(m0 + rbase + lrow)*KTOT + k0 + lcol]);
      async_copy16(&Bs[rbase*BK], &wt[(size_t)(n0 + rbase + lrow)*KTOT + k0 + lcol]);
    }
    asm volatile("s_waitcnt vmcnt(0)" ::: "memory");
    __syncthreads();
    #pragma unroll
    for (int ks = 0; ks < 2; ++ks) {
      bf16x8 af[4], bfr[4];
      #pragma unroll
      for (int mi = 0; mi < 4; ++mi)
        af[mi] = *reinterpret_cast<const bf16x8*>(&As[(wm + mi*16 + ln)*BK + ks*32 + lg*8]);
      #pragma unroll
      for (int ni = 0; ni < 4; ++ni)
        bfr[ni] = *reinterpret_cast<const bf16x8*>(&Bs[(wn + ni*16 + ln)*BK + ks*32 + lg*8]);
      #pragma unroll
      for (int mi = 0; mi < 4; ++mi)
        #pragma unroll
        for (int ni = 0; ni < 4; ++ni)
          acc[mi][ni] = __builtin_amdgcn_mfma_f32_16x16x32_bf16(af[mi], bfr[ni], acc[mi][ni], 0, 0, 0);
    }
    __syncthreads();
  }

  int r4 = lg * 4;
  #pragma unroll
  for (int mi = 0; mi < 4; ++mi) {
    #pragma unroll
    for (int ni = 0; ni < 4; ++ni) {
      int nc = n0 + wn + ni*16 + ln;
      int c  = nc >> 10;
      int hd = nc & 1023;
      int h = hd >> 6, d = hd & 63;
      float bias = bqkv[hd*3 + c];
      float qs = (c == 0) ? QSCALE : 1.0f;   // fold softmax scale into Q
      #pragma unroll
      for (int j = 0; j < 4; ++j) {
        int m = m0 + wm + mi*16 + r4 + j;
        int n = m >> 11, t = m & 2047;
        unsigned short val = f2bf((acc[mi][ni][j] + bias) * qs);
        size_t nh = (size_t)(n*NHEADS + h);
        if (c == 0)      Qb[((nh*SEQ + t) << 6) + d] = val;
        else if (c == 1) Kb[((nh*SEQ + t) << 6) + d] = val;
        else             Vt[((nh*HDIM + d) << 11) + t] = val;
      }
    }
  }
}

// ---------------------------------------------------------------- attention
// LDS-staged flash attention (T3-minimum 2-phase pipeline, guide §5.5).
// Block = 4 waves = 4 q-subtiles (64 q-rows), one head, full 2048-key sweep.
// K-tile [64 keys][64 d] and V-tile [64 d][64 keys] staged to LDS dbuf via
// global_load_lds (width 16), staged ONCE per block. Row-major 128B rows are
// a 16-way bank conflict -> rule-21 swizzle: LINEAR LDS dest + inverse-XOR
// source (seg ^= row&7 on the 16B segment) + XOR on the ds_read address.
// MFMA fragment maps (HW-validated R1/R4):
//   A-frag: row=l&15, k=8*(l>>4)+j   B-frag: col=l&15, k=8*(l>>4)+j
//   C/D   : col=l&15, row=4*(l>>4)+reg
// Softmax: per-lane local max + T13 defer-max; deferred row-sum (one
// cross-lane reduce after the loop); P via per-wave LDS (validated packing).
#define PROW    72                  // P row stride, bf16 elems (144 B)
#define POFF    32768               // P regions start (after K/V staging)
#define PBYTES  2304                // 16 rows x 144 B per wave
#define OREGION 4352                // epilogue obuf: 16 x 68 f32 (reuses staging)
__launch_bounds__(256)
__global__ void attn_kernel(const unsigned short* __restrict__ Qb,
                            const unsigned short* __restrict__ Kb,
                            const unsigned short* __restrict__ Vt,
                            float* __restrict__ out) {
  __shared__ __align__(16) unsigned char smem[POFF + 4*PBYTES]; // 41984 B
  int tid = threadIdx.x;
  int w = tid >> 6, l = tid & 63;
  int ln = l & 15, lg = l >> 4;

  unsigned short* Pw  = (unsigned short*)(smem + POFF + w * PBYTES);
  float*          obw = (float*)         (smem + w * OREGION); // post-loop only

  // XCD clustering: 1024 blocks, 8 XCDs -> each XCD owns 4 heads
  int fid  = blockIdx.x;
  int xcd  = fid & 7, idx = fid >> 3;       // idx 0..127
  int bh   = xcd * 4 + (idx >> 5);          // 0..31
  int qblk = idx & 31;                      // 0..31 (64 q-rows each)
  int q0   = qblk * 64 + w * 16;

  const unsigned short* Qh = Qb + (size_t)bh * SEQ * HDIM;
  const unsigned short* Kh = Kb + (size_t)bh * SEQ * HDIM;
  const unsigned short* Vh = Vt + (size_t)bh * HDIM * SEQ;

  // staging mapping: wave w, call c covers rows c*32 + w*8 + (l>>3)
  int srow8 = w*8 + (l >> 3);     // row within 32-row half (plus c*32)
  int sseg  = l & 7;              // 16B segment within the 128B row

  // Q B-fragments (col = q = ln), d-windows dw=0,1
  bf16x8 qf[2];
  #pragma unroll
  for (int dw = 0; dw < 2; ++dw)
    qf[dw] = *reinterpret_cast<const bf16x8*>(&Qh[(size_t)(q0 + ln)*HDIM + dw*32 + lg*8]);

  const f32x4 zero4 = {0.f, 0.f, 0.f, 0.f};
  f32x4 o[4];
  #pragma unroll
  for (int db = 0; db < 4; ++db) o[db] = zero4;
  f32x4 psum4 = zero4;
  float mrow = -INFINITY;

  // STAGE one 64-key tile: K[key][d] + V[d][key], inverse-swizzled source
  #define STAGE(BUF, KEY0)                                                    \
  do {                                                                        \
    _Pragma("unroll")                                                         \
    for (int c = 0; c < 2; ++c) {                                             \
      int row = c*32 + srow8;                                                 \
      int sg  = sseg ^ (row & 7);                                             \
      async_copy16(smem + (BUF)*8192 + c*4096 + w*1024,                       \
                   &Kh[(size_t)((KEY0) + row)*HDIM + sg*8]);                  \
      async_copy16(smem + 16384 + (BUF)*8192 + c*4096 + w*1024,               \
                   &Vh[(size_t)row*SEQ + (KEY0) + sg*8]);                     \
    }                                                                         \
  } while (0)

  STAGE(0, 0);
  __syncthreads();   // drains vmcnt(0): buffer 0 ready

  int xorE = (ln & 7) << 3;   // element-index XOR for swizzled ds_read

  for (int kv = 0; kv < 32; ++kv) {
    int cur  = kv & 1;
    int nkey = (kv < 31) ? (kv + 1) * 64 : kv * 64;
    STAGE(cur ^ 1, nkey);     // prefetch next tile (drained by the barrier)

    const unsigned short* Kc = (const unsigned short*)(smem + cur*8192);
    const unsigned short* Vc = (const unsigned short*)(smem + 16384 + cur*8192);

    // ---- S^T: 4 key-blocks x 2 d-windows (K A-frags from swizzled LDS)
    f32x4 s[4];
    #pragma unroll
    for (int kb = 0; kb < 4; ++kb) {
      int r = kb*16 + ln;
      bf16x8 k0 = *reinterpret_cast<const bf16x8*>(&Kc[r*HDIM + ((     lg*8) ^ xorE)]);
      bf16x8 k1 = *reinterpret_cast<const bf16x8*>(&Kc[r*HDIM + ((32 + lg*8) ^ xorE)]);
      f32x4 t0 = __builtin_amdgcn_mfma_f32_16x16x32_bf16(k0, qf[0], zero4, 0, 0, 0);
      s[kb]    = __builtin_amdgcn_mfma_f32_16x16x32_bf16(k1, qf[1], t0,    0, 0, 0);
    }

    // ---- per-lane local max over this lane's 16 keys (no cross-lane)
    f32x4 m4 = vmax4(vmax4(s[0], s[1]), vmax4(s[2], s[3]));
    float localmax = fmaxf(fmaxf(m4[0], m4[1]), fmaxf(m4[2], m4[3]));

    // ---- T13 defer-max: full reduce+rescale only when max grows (rare)
    if (!__all(localmax <= mrow + 8.f)) {
      float pm = localmax;
      pm = fmaxf(pm, __shfl_xor(pm, 16));
      pm = fmaxf(pm, __shfl_xor(pm, 32));
      float mn  = fmaxf(mrow, pm);
      float scl = __builtin_amdgcn_exp2f(mrow - mn);
      mrow = mn;
      psum4 *= scl;
      #pragma unroll
      for (int db = 0; db < 4; ++db)
        #pragma unroll
        for (int r = 0; r < 4; ++r) o[db][r] *= scl;
    }

    // ---- P = exp2(S - m); accumulate per-lane partial sums in registers
    #pragma unroll
    for (int kb = 0; kb < 4; ++kb) {
      #pragma unroll
      for (int r = 0; r < 4; ++r)
        s[kb][r] = __builtin_amdgcn_exp2f(s[kb][r] - mrow);
      psum4 += s[kb];
    }

    // ---- P -> LDS, row q=ln, col key (validated f2bf pair packing)
    #pragma unroll
    for (int kb = 0; kb < 4; ++kb) {
      unsigned pa = (unsigned)f2bf(s[kb][0]) | ((unsigned)f2bf(s[kb][1]) << 16);
      unsigned pb = (unsigned)f2bf(s[kb][2]) | ((unsigned)f2bf(s[kb][3]) << 16);
      uint2 pk; pk.x = pa; pk.y = pb;
      *reinterpret_cast<uint2*>(&Pw[ln*PROW + kb*16 + 4*lg]) = pk;
    }

    // ---- PV: A = V^T frags (swizzled LDS), B = P^T from LDS
    #pragma unroll
    for (int kw = 0; kw < 2; ++kw) {
      bf16x8 pb = *reinterpret_cast<const bf16x8*>(&Pw[ln*PROW + kw*32 + lg*8]);
      #pragma unroll
      for (int db = 0; db < 4; ++db) {
        int r = db*16 + ln;
        bf16x8 vfr = *reinterpret_cast<const bf16x8*>(
            &Vc[r*64 + ((kw*32 + lg*8) ^ xorE)]);
        o[db] = __builtin_amdgcn_mfma_f32_16x16x32_bf16(vfr, pb, o[db], 0, 0, 0);
      }
    }

    __syncthreads();   // drains vmcnt(0) (next buffer staged) + LDS
  }
  #undef STAGE

  // ---- post-loop: row-sum reduce (once), normalize, transpose, store
  float ls = (psum4[0] + psum4[1]) + (psum4[2] + psum4[3]);
  ls += __shfl_xor(ls, 16);
  ls += __shfl_xor(ls, 32);
  float inv = 1.f / ls;

  #pragma unroll
  for (int db = 0; db < 4; ++db)
    #pragma unroll
    for (int r = 0; r < 4; ++r)
      obw[ln*68 + db*16 + 4*lg + r] = o[db][r] * inv;
  asm volatile("s_waitcnt lgkmcnt(0)" ::: "memory");
  int n = bh >> 4, h = bh & 15;
  #pragma unroll
  for (int p = 0; p < 4; ++p) {
    int q = p*4 + lg;
    f32x4 vv = *reinterpret_cast<const f32x4*>(&obw[q*68 + ln*4]);
    *reinterpret_cast<f32x4*>(
        &out[((size_t)(n*SEQ + q0 + q))*DMODEL + h*HDIM + ln*4]) = vv;
  }
}

// ---------------------------------------------------------------- launcher
extern "C" void kernel_launch(void* const* d_in, const int* in_sizes, int n_in,
                              void* d_out, int out_size, void* d_ws, size_t ws_size,
                              hipStream_t stream) {
  const float* x    = (const float*)d_in[0];
  // d_in[1] = mask: constant shift along query axis inside softmax -> no-op
  const float* Wq   = (const float*)d_in[2];
  const float* bq   = (const float*)d_in[3];
  float* out = (float*)d_out;

  unsigned short* xb = (unsigned short*)d_ws;                    // [4096][1024]
  unsigned short* wt = xb + (size_t)MTOT*KTOT;                   // [3072][1024]
  unsigned short* Qb = wt + (size_t)NTOT*KTOT;                   // [32][2048][64]
  unsigned short* Kb = Qb + (size_t)NB*NHEADS*SEQ*HDIM;          // [32][2048][64]
  unsigned short* Vt = Kb + (size_t)NB*NHEADS*SEQ*HDIM;          // [32][64][2048]

  convert_x_kernel<<<(MTOT*KTOT/8)/256, 256, 0, stream>>>(x, xb);
  transpose_w_kernel<<<dim3(NTOT/64, KTOT/64), 256, 0, stream>>>(Wq, wt);
  qkv_gemm_kernel<<<dim3(NTOT/BN, MTOT/BM), 256, 0, stream>>>(xb, wt, bq, Qb, Kb, Vt);
  attn_kernel<<<1024, 256, 0, stream>>>(Qb, Kb, Vt, out);
}

// Round 8
// 126.942 us; speedup vs baseline: 2.8235x; 1.1731x over previous
//
#include <hip/hip_runtime.h>
#include <hip/hip_bf16.h>
#include <stdint.h>

// Sizes (fixed for this problem)
#define NHEADS 16
#define HDIM   64
#define DMODEL 1024
#define SEQ    2048
#define NB     2
#define MTOT   (NB*SEQ)     // 4096 rows of x
#define NTOT   (3*DMODEL)   // 3072 qkv cols
#define KTOT   DMODEL       // 1024

// fold (1/8)*log2(e) into Q so softmax runs in exp2 domain
#define QSCALE 0.18033688011112042f

typedef __attribute__((ext_vector_type(8)))  short          bf16x8;
typedef __attribute__((ext_vector_type(4)))  float          f32x4;
typedef __attribute__((ext_vector_type(8)))  unsigned short u16x8;

__device__ __forceinline__ unsigned short f2bf(float f) {
  unsigned u = __builtin_bit_cast(unsigned, f);
  u += 0x7fffu + ((u >> 16) & 1u);          // round-to-nearest-even
  return (unsigned short)(u >> 16);
}

__device__ __forceinline__ f32x4 vmax4(f32x4 a, f32x4 b) {
  f32x4 r;
  r[0]=fmaxf(a[0],b[0]); r[1]=fmaxf(a[1],b[1]);
  r[2]=fmaxf(a[2],b[2]); r[3]=fmaxf(a[3],b[3]);
  return r;
}

__device__ __forceinline__ void async_copy16(void* lds, const void* g) {
  __builtin_amdgcn_global_load_lds(
      (const __attribute__((address_space(1))) unsigned int*)g,
      (__attribute__((address_space(3))) unsigned int*)lds, 16, 0, 0);
}

// ---------------------------------------------------------------- convert x
__global__ void convert_x_kernel(const float* __restrict__ x,
                                 unsigned short* __restrict__ xb) {
  int i = blockIdx.x * 256 + threadIdx.x;
  const f32x4* xv = reinterpret_cast<const f32x4*>(x);
  f32x4 a = xv[2*i];
  f32x4 b = xv[2*i + 1];
  u16x8 r;
  r[0]=f2bf(a[0]); r[1]=f2bf(a[1]); r[2]=f2bf(a[2]); r[3]=f2bf(a[3]);
  r[4]=f2bf(b[0]); r[5]=f2bf(b[1]); r[6]=f2bf(b[2]); r[7]=f2bf(b[3]);
  reinterpret_cast<u16x8*>(xb)[i] = r;
}

// --------------------------------------- transpose + permute + convert W
__global__ void transpose_w_kernel(const float* __restrict__ W,
                                   unsigned short* __restrict__ Wt) {
  __shared__ float tile[64][65];
  int j0 = blockIdx.x * 64;
  int k0 = blockIdx.y * 64;
  int tid = threadIdx.x;
  int lr = tid >> 6;
  int lc = tid & 63;
  #pragma unroll
  for (int i = 0; i < 16; ++i) {
    int r = i*4 + lr;
    tile[r][lc] = W[(size_t)(k0 + r)*NTOT + j0 + lc];
  }
  __syncthreads();
  #pragma unroll
  for (int i = 0; i < 16; ++i) {
    int jr = i*4 + lr;
    int j  = j0 + jr;
    int oc = (j % 3)*DMODEL + (j / 3);
    Wt[(size_t)oc*KTOT + k0 + lc] = f2bf(tile[lc][jr]);
  }
}

// ---------------------------------------------------------------- QKV GEMM
#define BM 128
#define BN 128
#define BK 64
__launch_bounds__(256)
__global__ void qkv_gemm_kernel(const unsigned short* __restrict__ xb,
                                const unsigned short* __restrict__ wt,
                                const float* __restrict__ bqkv,
                                unsigned short* __restrict__ Qb,
                                unsigned short* __restrict__ Kb,
                                unsigned short* __restrict__ Vt) {
  __shared__ __align__(16) unsigned short As[BM*BK];
  __shared__ __align__(16) unsigned short Bs[BN*BK];
  int tid = threadIdx.x;
  int w = tid >> 6, l = tid & 63;
  int m0 = blockIdx.y * BM;
  int n0 = blockIdx.x * BN;
  int lrow = l >> 3;
  int lcol = (l & 7) * 8;
  int wm = (w >> 1) * 64;
  int wn = (w & 1) * 64;
  int ln = l & 15, lg = l >> 4;

  f32x4 acc[4][4];
  const f32x4 zero4 = {0.f, 0.f, 0.f, 0.f};
  #pragma unroll
  for (int i = 0; i < 4; ++i)
    #pragma unroll
    for (int j = 0; j < 4; ++j) acc[i][j] = zero4;

  for (int kt = 0; kt < KTOT/BK; ++kt) {
    int k0 = kt * BK;
    #pragma unroll
    for (int i = 0; i < 4; ++i) {
      int rbase = w*32 + i*8;
      async_copy16(&As[rbase*BK], &xb[(size_t)(m0 + rbase + lrow)*KTOT + k0 + lcol]);
      async_copy16(&Bs[rbase*BK], &wt[(size_t)(n0 + rbase + lrow)*KTOT + k0 + lcol]);
    }
    asm volatile("s_waitcnt vmcnt(0)" ::: "memory");
    __syncthreads();
    #pragma unroll
    for (int ks = 0; ks < 2; ++ks) {
      bf16x8 af[4], bfr[4];
      #pragma unroll
      for (int mi = 0; mi < 4; ++mi)
        af[mi] = *reinterpret_cast<const bf16x8*>(&As[(wm + mi*16 + ln)*BK + ks*32 + lg*8]);
      #pragma unroll
      for (int ni = 0; ni < 4; ++ni)
        bfr[ni] = *reinterpret_cast<const bf16x8*>(&Bs[(wn + ni*16 + ln)*BK + ks*32 + lg*8]);
      #pragma unroll
      for (int mi = 0; mi < 4; ++mi)
        #pragma unroll
        for (int ni = 0; ni < 4; ++ni)
          acc[mi][ni] = __builtin_amdgcn_mfma_f32_16x16x32_bf16(af[mi], bfr[ni], acc[mi][ni], 0, 0, 0);
    }
    __syncthreads();
  }

  int r4 = lg * 4;
  #pragma unroll
  for (int mi = 0; mi < 4; ++mi) {
    #pragma unroll
    for (int ni = 0; ni < 4; ++ni) {
      int nc = n0 + wn + ni*16 + ln;
      int c  = nc >> 10;
      int hd = nc & 1023;
      int h = hd >> 6, d = hd & 63;
      float bias = bqkv[hd*3 + c];
      float qs = (c == 0) ? QSCALE : 1.0f;   // fold softmax scale into Q
      #pragma unroll
      for (int j = 0; j < 4; ++j) {
        int m = m0 + wm + mi*16 + r4 + j;
        int n = m >> 11, t = m & 2047;
        unsigned short val = f2bf((acc[mi][ni][j] + bias) * qs);
        size_t nh = (size_t)(n*NHEADS + h);
        if (c == 0)      Qb[((nh*SEQ + t) << 6) + d] = val;
        else if (c == 1) Kb[((nh*SEQ + t) << 6) + d] = val;
        else             Vt[((nh*HDIM + d) << 11) + t] = val;
      }
    }
  }
}

// ---------------------------------------------------------------- attention
// LDS-staged flash attention (T3 2-phase pipeline), R8: 8-wave blocks.
// Block = 8 waves = 128 q-rows, one head, full 2048-key sweep. K-tile
// [64 keys][64 d] and V-tile [64 d][64 keys] staged to LDS dbuf via
// global_load_lds (width 16), staged ONCE per 128 q-rows. Rule-21 swizzle:
// linear LDS dest + inverse-XOR source (seg ^= row&7) + XOR on ds_read.
// MFMA fragment maps (HW-validated R1/R4/R7):
//   A-frag: row=l&15, k=8*(l>>4)+j   B-frag: col=l&15, k=8*(l>>4)+j
//   C/D   : col=l&15, row=4*(l>>4)+reg
// Softmax: per-lane local max + T13 defer-max; deferred row-sum; P packed
// with v_cvt_pk_bf16_f32 (T12 recipe, RNE — numerically identical to f2bf);
// P stride 176B (2-way conflicts, free, vs 144B's 8-way).
#define PROW    88                  // P row stride, bf16 elems (176 B)
#define POFF    32768               // P regions start (after K/V staging)
#define PBYTES  2816                // 16 rows x 176 B per wave
#define OREGION 4352                // epilogue obuf: 16 x 68 f32 (reuses staging)
__launch_bounds__(512)
__global__ void attn_kernel(const unsigned short* __restrict__ Qb,
                            const unsigned short* __restrict__ Kb,
                            const unsigned short* __restrict__ Vt,
                            float* __restrict__ out) {
  __shared__ __align__(16) unsigned char smem[POFF + 8*PBYTES]; // 55296 B
  int tid = threadIdx.x;
  int w = tid >> 6, l = tid & 63;
  int ln = l & 15, lg = l >> 4;

  unsigned short* Pw  = (unsigned short*)(smem + POFF + w * PBYTES);
  float*          obw = (float*)         (smem + w * OREGION); // post-loop only

  // XCD clustering: 512 blocks, 8 XCDs -> each XCD owns 4 heads
  int fid  = blockIdx.x;
  int xcd  = fid & 7, idx = fid >> 3;       // idx 0..63
  int bh   = xcd * 4 + (idx >> 4);          // 0..31
  int qblk = idx & 15;                      // 0..15 (128 q-rows each)
  int q0   = qblk * 128 + w * 16;

  const unsigned short* Qh = Qb + (size_t)bh * SEQ * HDIM;
  const unsigned short* Kh = Kb + (size_t)bh * SEQ * HDIM;
  const unsigned short* Vh = Vt + (size_t)bh * HDIM * SEQ;

  // staging mapping: 512 threads cover one 64x64 bf16 tile in ONE call
  int srow = w*8 + (l >> 3);      // row 0..63
  int sseg = (l & 7) ^ (srow & 7);// inverse-swizzled 16B segment

  // Q B-fragments (col = q = ln), d-windows dw=0,1
  bf16x8 qf[2];
  #pragma unroll
  for (int dw = 0; dw < 2; ++dw)
    qf[dw] = *reinterpret_cast<const bf16x8*>(&Qh[(size_t)(q0 + ln)*HDIM + dw*32 + lg*8]);

  const f32x4 zero4 = {0.f, 0.f, 0.f, 0.f};
  f32x4 o[4];
  #pragma unroll
  for (int db = 0; db < 4; ++db) o[db] = zero4;
  f32x4 psum4 = zero4;
  float mrow = -INFINITY;

  // STAGE one 64-key tile: K[key][d] + V[d][key], inverse-swizzled source
  #define STAGE(BUF, KEY0)                                                    \
  do {                                                                        \
    async_copy16(smem + (BUF)*8192 + w*1024,                                  \
                 &Kh[(size_t)((KEY0) + srow)*HDIM + sseg*8]);                 \
    async_copy16(smem + 16384 + (BUF)*8192 + w*1024,                          \
                 &Vh[(size_t)srow*SEQ + (KEY0) + sseg*8]);                    \
  } while (0)

  STAGE(0, 0);
  __syncthreads();   // drains vmcnt(0): buffer 0 ready

  int xorE = (ln & 7) << 3;   // element-index XOR for swizzled ds_read

  for (int kv = 0; kv < 32; ++kv) {
    int cur  = kv & 1;
    int nkey = (kv < 31) ? (kv + 1) * 64 : kv * 64;
    STAGE(cur ^ 1, nkey);     // prefetch next tile (drained by the barrier)

    const unsigned short* Kc = (const unsigned short*)(smem + cur*8192);
    const unsigned short* Vc = (const unsigned short*)(smem + 16384 + cur*8192);

    // ---- S^T: 4 key-blocks x 2 d-windows (K A-frags from swizzled LDS)
    f32x4 s[4];
    #pragma unroll
    for (int kb = 0; kb < 4; ++kb) {
      int r = kb*16 + ln;
      bf16x8 k0 = *reinterpret_cast<const bf16x8*>(&Kc[r*HDIM + ((     lg*8) ^ xorE)]);
      bf16x8 k1 = *reinterpret_cast<const bf16x8*>(&Kc[r*HDIM + ((32 + lg*8) ^ xorE)]);
      f32x4 t0 = __builtin_amdgcn_mfma_f32_16x16x32_bf16(k0, qf[0], zero4, 0, 0, 0);
      s[kb]    = __builtin_amdgcn_mfma_f32_16x16x32_bf16(k1, qf[1], t0,    0, 0, 0);
    }

    // ---- per-lane local max over this lane's 16 keys (no cross-lane)
    f32x4 m4 = vmax4(vmax4(s[0], s[1]), vmax4(s[2], s[3]));
    float localmax = fmaxf(fmaxf(m4[0], m4[1]), fmaxf(m4[2], m4[3]));

    // ---- T13 defer-max: full reduce+rescale only when max grows (rare)
    if (!__all(localmax <= mrow + 8.f)) {
      float pm = localmax;
      pm = fmaxf(pm, __shfl_xor(pm, 16));
      pm = fmaxf(pm, __shfl_xor(pm, 32));
      float mn  = fmaxf(mrow, pm);
      float scl = __builtin_amdgcn_exp2f(mrow - mn);
      mrow = mn;
      psum4 *= scl;
      #pragma unroll
      for (int db = 0; db < 4; ++db)
        #pragma unroll
        for (int r = 0; r < 4; ++r) o[db][r] *= scl;
    }

    // ---- P = exp2(S - m); accumulate per-lane partial sums in registers
    #pragma unroll
    for (int kb = 0; kb < 4; ++kb) {
      #pragma unroll
      for (int r = 0; r < 4; ++r)
        s[kb][r] = __builtin_amdgcn_exp2f(s[kb][r] - mrow);
      psum4 += s[kb];
    }

    // ---- P -> LDS via v_cvt_pk_bf16_f32 (T12; RNE, same bits as f2bf)
    #pragma unroll
    for (int kb = 0; kb < 4; ++kb) {
      uint2 pk;
      asm("v_cvt_pk_bf16_f32 %0, %1, %2" : "=v"(pk.x) : "v"(s[kb][0]), "v"(s[kb][1]));
      asm("v_cvt_pk_bf16_f32 %0, %1, %2" : "=v"(pk.y) : "v"(s[kb][2]), "v"(s[kb][3]));
      *reinterpret_cast<uint2*>(&Pw[ln*PROW + kb*16 + 4*lg]) = pk;
    }

    // ---- PV: A = V^T frags (swizzled LDS), B = P^T from LDS
    #pragma unroll
    for (int kw = 0; kw < 2; ++kw) {
      bf16x8 pb = *reinterpret_cast<const bf16x8*>(&Pw[ln*PROW + kw*32 + lg*8]);
      #pragma unroll
      for (int db = 0; db < 4; ++db) {
        int r = db*16 + ln;
        bf16x8 vfr = *reinterpret_cast<const bf16x8*>(
            &Vc[r*64 + ((kw*32 + lg*8) ^ xorE)]);
        o[db] = __builtin_amdgcn_mfma_f32_16x16x32_bf16(vfr, pb, o[db], 0, 0, 0);
      }
    }

    __syncthreads();   // drains vmcnt(0) (next buffer staged) + LDS
  }
  #undef STAGE

  // ---- post-loop: row-sum reduce (once), normalize, transpose, store
  float ls = (psum4[0] + psum4[1]) + (psum4[2] + psum4[3]);
  ls += __shfl_xor(ls, 16);
  ls += __shfl_xor(ls, 32);
  float inv = 1.f / ls;

  #pragma unroll
  for (int db = 0; db < 4; ++db)
    #pragma unroll
    for (int r = 0; r < 4; ++r)
      obw[ln*68 + db*16 + 4*lg + r] = o[db][r] * inv;
  asm volatile("s_waitcnt lgkmcnt(0)" ::: "memory");
  int n = bh >> 4, h = bh & 15;
  #pragma unroll
  for (int p = 0; p < 4; ++p) {
    int q = p*4 + lg;
    f32x4 vv = *reinterpret_cast<const f32x4*>(&obw[q*68 + ln*4]);
    *reinterpret_cast<f32x4*>(
        &out[((size_t)(n*SEQ + q0 + q))*DMODEL + h*HDIM + ln*4]) = vv;
  }
}

// ---------------------------------------------------------------- launcher
extern "C" void kernel_launch(void* const* d_in, const int* in_sizes, int n_in,
                              void* d_out, int out_size, void* d_ws, size_t ws_size,
                              hipStream_t stream) {
  const float* x    = (const float*)d_in[0];
  // d_in[1] = mask: constant shift along query axis inside softmax -> no-op
  const float* Wq   = (const float*)d_in[2];
  const float* bq   = (const float*)d_in[3];
  float* out = (float*)d_out;

  unsigned short* xb = (unsigned short*)d_ws;                    // [4096][1024]
  unsigned short* wt = xb + (size_t)MTOT*KTOT;                   // [3072][1024]
  unsigned short* Qb = wt + (size_t)NTOT*KTOT;                   // [32][2048][64]
  unsigned short* Kb = Qb + (size_t)NB*NHEADS*SEQ*HDIM;          // [32][2048][64]
  unsigned short* Vt = Kb + (size_t)NB*NHEADS*SEQ*HDIM;          // [32][64][2048]

  convert_x_kernel<<<(MTOT*KTOT/8)/256, 256, 0, stream>>>(x, xb);
  transpose_w_kernel<<<dim3(NTOT/64, KTOT/64), 256, 0, stream>>>(Wq, wt);
  qkv_gemm_kernel<<<dim3(NTOT/BN, MTOT/BM), 256, 0, stream>>>(xb, wt, bq, Qb, Kb, Vt);
  attn_kernel<<<512, 512, 0, stream>>>(Qb, Kb, Vt, out);
}